// Round 6
// baseline (128.938 us; speedup 1.0000x reference)
//
#include <hip/hip_runtime.h>
#include <cstdint>

namespace {

typedef _Float16 half2v __attribute__((ext_vector_type(2)));

constexpr int KFS = 51;
constexpr int NB = 2, NC = 3, HH = 512, WW = 512;
constexpr int HP = HH + KFS - 1;   // 562
constexpr int WP = WW + KFS - 1;   // 562
constexpr int TW = 128, TH = 8, PX = 2;
constexpr int NTX = TW / PX;          // 64 lanes across x -> full wave per row
constexpr int NTHREADS = NTX * TH;    // 512 (8 waves)
constexpr int TILEW = TW + KFS - 1;   // 178 input cols per tile
constexpr int NROWS = TH + KFS - 1;   // 58 input rows per tile
constexpr int QPR = TILEW / 2;        // 89 f16-pairs per row
constexpr int PAIRS = 90;             // row stride in dwords
constexpr int CTILE = NROWS * PAIRS;  // 5220 dwords per channel
constexpr size_t VSTR = (size_t)HH * WW;

__device__ __forceinline__ uint32_t pack2(float a, float b) {
  half2v p;
  p.x = (_Float16)a;  // RNE
  p.y = (_Float16)b;
  return __builtin_bit_cast(uint32_t, p);
}

__device__ __forceinline__ float fdot2(uint32_t a, uint32_t b, float c) {
#if defined(__has_builtin) && __has_builtin(__builtin_amdgcn_fdot2)
  return __builtin_amdgcn_fdot2(__builtin_bit_cast(half2v, a),
                                __builtin_bit_cast(half2v, b), c, false);
#else
  float r;
  asm("v_dot2_f32_f16 %0, %1, %2, %3" : "=v"(r) : "v"(a), "v"(b), "v"(c));
  return r;
#endif
}

// Pass over taps j = JC..JC+J-1 (JC even). PX=2: pixels p=0,1.
// Window pairs ev[k] = (w[2k], w[2k+1]) at pair base tx + JC/2 (stride-1 across
// lanes -> conflict-free b32 / ds_read2_b32).
//   p=0: hz0 = sum_k ev[k] . (hx[2k],   hx[2k+1])   k < NHE
//   p=1: hz1 = sum_k ev[k] . (hy[2k-1], hy[2k])     k < NHM  (hy[-1]=0)
template <int JC, int J>
__device__ __forceinline__ void run_pass(const uint32_t* __restrict__ tile,
                                         const float* __restrict__ v2,
                                         const float* __restrict__ h3,
                                         float (&acc)[NC][PX],
                                         int y, int x0, int tx, int ty) {
  constexpr int NHE = (J + 1) / 2;
  constexpr int NHM = (J + 2) / 2;  // also the ev count
  constexpr int QC = JC / 2;

  // Pack h coefficients incrementally (bounded liveness).
  uint32_t heX[NHE], hmY[NHM];
  {
    float prev_y = 0.f;
    #pragma unroll
    for (int k = 0; k < NHM; ++k) {
      float2 a = make_float2(0.f, 0.f), bq = make_float2(0.f, 0.f);
      if (2 * k < J)
        a = *reinterpret_cast<const float2*>(h3 + ((size_t)(JC + 2 * k) * HH + y) * WW + x0);
      if (2 * k + 1 < J)
        bq = *reinterpret_cast<const float2*>(h3 + ((size_t)(JC + 2 * k + 1) * HH + y) * WW + x0);
      if (k < NHE) heX[k] = pack2(a.x, bq.x);
      hmY[k] = pack2(prev_y, a.y);
      prev_y = bq.y;
    }
  }

  // v prefetch, depth 3, statically rotated.
  const float* vp = v2 + (size_t)y * WW + x0;
  float2 vr0 = *reinterpret_cast<const float2*>(vp);
  float2 vr1 = *reinterpret_cast<const float2*>(vp + VSTR);
  float2 vr2 = *reinterpret_cast<const float2*>(vp + 2 * VSTR);

  int tb = ty * PAIRS + tx + QC;  // dword index within a channel tile

  auto step = [&](int i, float2& vslot) {
    const float2 v4 = vslot;
    const int ip = (i + 3 < KFS) ? i + 3 : KFS - 1;
    vslot = *reinterpret_cast<const float2*>(vp + (size_t)ip * VSTR);

    #pragma unroll
    for (int c = 0; c < NC; ++c) {
      const uint32_t* wp = tile + c * CTILE + tb;
      uint32_t ev[NHM];
      #pragma unroll
      for (int k = 0; k < NHM; ++k) ev[k] = wp[k];  // ds_read2_b32-fusable

      float hz0 = 0.f, hz1 = 0.f;
      #pragma unroll
      for (int k = 0; k < NHE; ++k) hz0 = fdot2(ev[k], heX[k], hz0);
      #pragma unroll
      for (int k = 0; k < NHM; ++k) hz1 = fdot2(ev[k], hmY[k], hz1);

      acc[c][0] = fmaf(v4.x, hz0, acc[c][0]);
      acc[c][1] = fmaf(v4.y, hz1, acc[c][1]);
    }
    tb += PAIRS;
  };

  #pragma unroll 1
  for (int ii = 0; ii < KFS / 3; ++ii) {
    step(3 * ii + 0, vr0);
    step(3 * ii + 1, vr1);
    step(3 * ii + 2, vr2);
  }
}

__global__ __launch_bounds__(NTHREADS, 4)
void sepconv_kernel(const float* __restrict__ in1, const float* __restrict__ in2,
                    const float* __restrict__ in3, float* __restrict__ out) {
  __shared__ uint32_t tile[NC * CTILE];  // 62,640 B: 3 channels, f16 pairs

  const int t = threadIdx.x;
  const int tx = t & (NTX - 1);
  const int ty = t >> 6;
  const int x0t = blockIdx.x * TW;
  const int y0t = blockIdx.y * TH;
  const int b = blockIdx.z;
  const int x0 = x0t + tx * PX;
  const int y = y0t + ty;

  const float* in1b = in1 + (size_t)b * NC * HP * WP;
  const float* v2 = in2 + (size_t)b * KFS * HH * WW;
  const float* h3 = in3 + (size_t)b * KFS * HH * WW;

  // Stage all 3 channel tiles once: f32 global -> f16 pairs in LDS (linear).
  constexpr int NU = NC * NROWS * QPR;  // 15486 pair-units
  for (int e = t; e < NU; e += NTHREADS) {
    const int c = e / (NROWS * QPR);
    const int rem = e - c * (NROWS * QPR);
    const int r = rem / QPR;
    const int q = rem - r * QPR;
    const float2 g = *reinterpret_cast<const float2*>(
        in1b + ((size_t)c * HP + y0t + r) * WP + x0t + 2 * q);
    tile[c * CTILE + r * PAIRS + q] = pack2(g.x, g.y);
  }
  __syncthreads();

  float acc[NC][PX];
  #pragma unroll
  for (int c = 0; c < NC; ++c)
    #pragma unroll
    for (int p = 0; p < PX; ++p) acc[c][p] = 0.f;

  run_pass<0, 16>(tile, v2, h3, acc, y, x0, tx, ty);
  run_pass<16, 16>(tile, v2, h3, acc, y, x0, tx, ty);
  run_pass<32, 19>(tile, v2, h3, acc, y, x0, tx, ty);

  float* outb = out + (size_t)b * NC * HH * WW;
  #pragma unroll
  for (int c = 0; c < NC; ++c) {
    float2 o;
    o.x = acc[c][0];
    o.y = acc[c][1];
    *reinterpret_cast<float2*>(outb + ((size_t)c * HH + y) * WW + x0) = o;
  }
}

}  // namespace

extern "C" void kernel_launch(void* const* d_in, const int* in_sizes, int n_in,
                              void* d_out, int out_size, void* d_ws, size_t ws_size,
                              hipStream_t stream) {
  const float* in1 = (const float*)d_in[0];
  const float* in2 = (const float*)d_in[1];
  const float* in3 = (const float*)d_in[2];
  float* out = (float*)d_out;

  dim3 grid(WW / TW, HH / TH, NB);
  sepconv_kernel<<<grid, NTHREADS, 0, stream>>>(in1, in2, in3, out);
}

// Round 7
// 128.066 us; speedup vs baseline: 1.0068x; 1.0068x over previous
//
#include <hip/hip_runtime.h>
#include <cstdint>

namespace {

typedef _Float16 half2v __attribute__((ext_vector_type(2)));
typedef unsigned int uint2v __attribute__((ext_vector_type(2)));

constexpr int KFS = 51;
constexpr int NB = 2, NC = 3, HH = 512, WW = 512;
constexpr int HP = HH + KFS - 1;   // 562
constexpr int WP = WW + KFS - 1;   // 562
constexpr int TW = 128, TH = 8, PX = 4;
constexpr int NTX = TW / PX;          // 32
constexpr int NTHREADS = NTX * TH;    // 256
constexpr int TILEW = TW + KFS - 1;   // 178 input cols per tile
constexpr int QPR = TILEW / 2;        // 89 f16-pairs per row
constexpr int PAIRS = 90;             // row stride in dwords (even)
constexpr int ISPLIT0 = 27;           // taps [0,27) / [27,51): both %3==0
constexpr int RMAX = ISPLIT0 + TH - 1;  // 34 rows max per block
constexpr int CTILE = RMAX * PAIRS;     // 3060 dwords per channel
constexpr size_t VSTR = (size_t)HH * WW;

__device__ __forceinline__ uint32_t pack2(float a, float b) {
  half2v p;
  p.x = (_Float16)a;  // RNE
  p.y = (_Float16)b;
  return __builtin_bit_cast(uint32_t, p);
}

__device__ __forceinline__ float fdot2(uint32_t a, uint32_t b, float c) {
#if defined(__has_builtin) && __has_builtin(__builtin_amdgcn_fdot2)
  return __builtin_amdgcn_fdot2(__builtin_bit_cast(half2v, a),
                                __builtin_bit_cast(half2v, b), c, false);
#else
  float r;
  asm("v_dot2_f32_f16 %0, %1, %2, %3" : "=v"(r) : "v"(a), "v"(b), "v"(c));
  return r;
#endif
}

// Pass over taps j = JC..JC+J-1 (JC multiple of 4 -> even pair base -> b64).
// Window pairs ev[k] = (w[2k], w[2k+1]) relative to col base 4*tx+JC.
//   p=0: ev[k].(hx[2k],  hx[2k+1])  k=0..NHE-1
//   p=1: ev[k].(hy[2k-1],hy[2k])    k=0..NHM-1
//   p=2: ev[k].(hz[2k-2],hz[2k-1])  k=1..NHE
//   p=3: ev[k].(hw[2k-3],hw[2k-2])  k=1..NHM
template <int JC, int J>
__device__ __forceinline__ void run_pass(const uint32_t* __restrict__ tile,
                                         const float* __restrict__ v2,
                                         const float* __restrict__ h3,
                                         float (&acc)[NC][PX],
                                         int y, int x0, int tx, int ty,
                                         int i0, int cnt3) {
  constexpr int NHE = (J + 1) / 2;
  constexpr int NHM = (J + 2) / 2;
  constexpr int NPAIR = NHM + 1;
  constexpr int NEV2 = (NPAIR + 1) / 2;
  constexpr int QC = JC / 2;
  static_assert((QC & 1) == 0, "pair base must be even for b64");

  // Pack h registers (once per pass).
  float4 hb[J];
  #pragma unroll
  for (int j = 0; j < J; ++j)
    hb[j] = *reinterpret_cast<const float4*>(h3 + ((size_t)(JC + j) * HH + y) * WW + x0);

  uint32_t heX[NHE], heZ[NHE], hmY[NHM], hmW[NHM];
  #pragma unroll
  for (int k = 0; k < NHE; ++k) {
    const float ax = hb[2 * k].x, az = hb[2 * k].z;
    const float bx = (2 * k + 1 < J) ? hb[2 * k + 1].x : 0.f;
    const float bz = (2 * k + 1 < J) ? hb[2 * k + 1].z : 0.f;
    heX[k] = pack2(ax, bx);
    heZ[k] = pack2(az, bz);
  }
  #pragma unroll
  for (int k = 0; k < NHM; ++k) {
    const float ay = (2 * k - 1 >= 0) ? hb[2 * k - 1].y : 0.f;
    const float aw = (2 * k - 1 >= 0) ? hb[2 * k - 1].w : 0.f;
    const float by = (2 * k < J) ? hb[2 * k].y : 0.f;
    const float bw = (2 * k < J) ? hb[2 * k].w : 0.f;
    hmY[k] = pack2(ay, by);
    hmW[k] = pack2(aw, bw);
  }

  const int cnt = 3 * cnt3;
  // v prefetch over the block's tap range, depth 3, statically rotated.
  const float* vp = v2 + (size_t)i0 * VSTR + (size_t)y * WW + x0;
  float4 vr0 = *reinterpret_cast<const float4*>(vp);
  float4 vr1 = *reinterpret_cast<const float4*>(vp + VSTR);
  float4 vr2 = *reinterpret_cast<const float4*>(vp + 2 * VSTR);

  int tb = ty * PAIRS + 2 * tx + QC;  // even dword index within a channel tile

  auto step = [&](int i, float4& vslot) {
    const float4 v4 = vslot;
    const int ip = (i + 3 < cnt) ? i + 3 : cnt - 1;
    vslot = *reinterpret_cast<const float4*>(vp + (size_t)ip * VSTR);

    #pragma unroll
    for (int c = 0; c < NC; ++c) {
      const uint2v* wp2 = reinterpret_cast<const uint2v*>(tile + c * CTILE + tb);
      uint32_t ev[2 * NEV2];
      #pragma unroll
      for (int k = 0; k < NEV2; ++k) {
        const uint2v q = wp2[k];  // ds_read_b64
        ev[2 * k] = q.x;
        ev[2 * k + 1] = q.y;
      }

      float hz0 = 0.f, hz1 = 0.f, hz2 = 0.f, hz3 = 0.f;
      #pragma unroll
      for (int k = 0; k < NHE; ++k) hz0 = fdot2(ev[k], heX[k], hz0);
      #pragma unroll
      for (int k = 0; k < NHM; ++k) hz1 = fdot2(ev[k], hmY[k], hz1);
      #pragma unroll
      for (int k = 1; k <= NHE; ++k) hz2 = fdot2(ev[k], heZ[k - 1], hz2);
      #pragma unroll
      for (int k = 1; k <= NHM; ++k) hz3 = fdot2(ev[k], hmW[k - 1], hz3);

      acc[c][0] = fmaf(v4.x, hz0, acc[c][0]);
      acc[c][1] = fmaf(v4.y, hz1, acc[c][1]);
      acc[c][2] = fmaf(v4.z, hz2, acc[c][2]);
      acc[c][3] = fmaf(v4.w, hz3, acc[c][3]);
    }
    tb += PAIRS;
  };

  #pragma unroll 1
  for (int ii = 0; ii < cnt3; ++ii) {
    step(3 * ii + 0, vr0);
    step(3 * ii + 1, vr1);
    step(3 * ii + 2, vr2);
  }
}

__global__ __launch_bounds__(NTHREADS, 4)
void sepconv_kernel(const float* __restrict__ in1, const float* __restrict__ in2,
                    const float* __restrict__ in3, float* __restrict__ out) {
  __shared__ uint32_t tile[NC * CTILE];  // 36,720 B

  const int t = threadIdx.x;
  const int tx = t & (NTX - 1);
  const int ty = t >> 5;
  const int x0t = blockIdx.x * TW;
  const int y0t = blockIdx.y * TH;
  const int iz = blockIdx.z & 1;
  const int b = blockIdx.z >> 1;
  const int x0 = x0t + tx * PX;
  const int y = y0t + ty;

  const int i0 = iz ? ISPLIT0 : 0;
  const int cnt = iz ? (KFS - ISPLIT0) : ISPLIT0;  // 24 or 27, both %3==0
  const int rows = cnt + TH - 1;                   // 31 or 34

  const float* in1b = in1 + (size_t)b * NC * HP * WP;
  const float* v2 = in2 + (size_t)b * KFS * HH * WW;
  const float* h3 = in3 + (size_t)b * KFS * HH * WW;

  // Stage this block's tap-range rows: f32 global -> f16 pairs in LDS.
  for (int e = t; e < NC * RMAX * QPR; e += NTHREADS) {
    const int c = e / (RMAX * QPR);
    const int rem = e - c * (RMAX * QPR);
    const int r = rem / QPR;
    const int q = rem - r * QPR;
    if (r < rows) {
      const float2 g = *reinterpret_cast<const float2*>(
          in1b + ((size_t)c * HP + y0t + i0 + r) * WP + x0t + 2 * q);
      tile[c * CTILE + r * PAIRS + q] = pack2(g.x, g.y);
    }
  }
  __syncthreads();

  float acc[NC][PX];
  #pragma unroll
  for (int c = 0; c < NC; ++c)
    #pragma unroll
    for (int p = 0; p < PX; ++p) acc[c][p] = 0.f;

  const int cnt3 = cnt / 3;
  run_pass<0, 16>(tile, v2, h3, acc, y, x0, tx, ty, i0, cnt3);
  run_pass<16, 16>(tile, v2, h3, acc, y, x0, tx, ty, i0, cnt3);
  run_pass<32, 19>(tile, v2, h3, acc, y, x0, tx, ty, i0, cnt3);

  float* outb = out + (size_t)b * NC * HH * WW;
  #pragma unroll
  for (int c = 0; c < NC; ++c) {
    float* op = outb + ((size_t)c * HH + y) * WW + x0;
    #pragma unroll
    for (int p = 0; p < PX; ++p) unsafeAtomicAdd(op + p, acc[c][p]);
  }
}

}  // namespace

extern "C" void kernel_launch(void* const* d_in, const int* in_sizes, int n_in,
                              void* d_out, int out_size, void* d_ws, size_t ws_size,
                              hipStream_t stream) {
  const float* in1 = (const float*)d_in[0];
  const float* in2 = (const float*)d_in[1];
  const float* in3 = (const float*)d_in[2];
  float* out = (float*)d_out;

  hipMemsetAsync(out, 0, (size_t)out_size * sizeof(float), stream);
  dim3 grid(WW / TW, HH / TH, NB * 2);
  sepconv_kernel<<<grid, NTHREADS, 0, stream>>>(in1, in2, in3, out);
}

// Round 8
// 119.709 us; speedup vs baseline: 1.0771x; 1.0698x over previous
//
#include <hip/hip_runtime.h>
#include <cstdint>

namespace {

typedef _Float16 half2v __attribute__((ext_vector_type(2)));
typedef unsigned int uint2v __attribute__((ext_vector_type(2)));

constexpr int KFS = 51;
constexpr int NB = 2, NC = 3, HH = 512, WW = 512;
constexpr int HP = HH + KFS - 1;   // 562
constexpr int WP = WW + KFS - 1;   // 562
constexpr int TW = 128;            // output tile width
constexpr int TH = 16;             // output tile height (2 rows per thread)
constexpr int PX = 4;
constexpr int NTX = TW / PX;       // 32
constexpr int NTY = 8;             // thread rows; each covers 2 output rows
constexpr int NTHREADS = NTX * NTY;  // 256
constexpr int TILEW = TW + KFS - 1;  // 178
constexpr int NROWS = TH + KFS - 1;  // 66 input rows per tile
constexpr int QPR = TILEW / 2;       // 89 f16-pairs per row
constexpr int PAIRS = 90;            // row stride in dwords (even)
constexpr int CTILE = NROWS * PAIRS; // 5940 dwords = 23.76 KB (one channel)
constexpr size_t VSTR = (size_t)HH * WW;
constexpr int XT = WW / TW;          // 4
constexpr int YT = HH / TH;          // 32
constexpr int NGRP = XT * YT * NB;   // 256 (x,y,b) groups
constexpr int NWG = NGRP * NC;       // 768 blocks

__device__ __forceinline__ uint32_t pack2(float a, float b) {
  half2v p;
  p.x = (_Float16)a;  // RNE
  p.y = (_Float16)b;
  return __builtin_bit_cast(uint32_t, p);
}

__device__ __forceinline__ float fdot2(uint32_t a, uint32_t b, float c) {
#if defined(__has_builtin) && __has_builtin(__builtin_amdgcn_fdot2)
  return __builtin_amdgcn_fdot2(__builtin_bit_cast(half2v, a),
                                __builtin_bit_cast(half2v, b), c, false);
#else
  float r;
  asm("v_dot2_f32_f16 %0, %1, %2, %3" : "=v"(r) : "v"(a), "v"(b), "v"(c));
  return r;
#endif
}

// Pass over taps j = JC..JC+J-1 (JC multiple of 4 -> even pair base -> b64).
// Each thread produces 2 output rows (y0, y0+1); one window-row read feeds both.
// Window pairs ev[q] = (w[2q], w[2q+1]) rel. col base 4*tx+JC. Pixel p uses
// w[p+j]; phase pairings (per output row, with that row's h):
//   p=0: ev[q].(h[2q],  h[2q+1])   q=0..NHE-1
//   p=1: ev[q].(h[2q-1],h[2q])     q=0..NHM-1
//   p=2: ev[q].(h[2q-2],h[2q-1])   q=1..NHE
//   p=3: ev[q].(h[2q-3],h[2q-2])   q=1..NHM
template <int JC, int J>
__device__ __forceinline__ void run_pass(const uint32_t* __restrict__ tile,
                                         const float* __restrict__ v2,
                                         const float* __restrict__ h3,
                                         float (&acc0)[PX], float (&acc1)[PX],
                                         int y0, int x0, int tx, int tyq) {
  constexpr int NHE = (J + 1) / 2;
  constexpr int NHM = (J + 2) / 2;
  constexpr int NEV2 = (NHM + 2) / 2;  // b64 reads covering pairs 0..NHM
  constexpr int QC = JC / 2;
  static_assert((QC & 1) == 0, "pair base must be even for b64");

  // h packs for out rows y0 and y1=y0+1, built incrementally.
  uint32_t heX0[NHE], heZ0[NHE], hmY0[NHM], hmW0[NHM];
  uint32_t heX1[NHE], heZ1[NHE], hmY1[NHM], hmW1[NHM];
  {
    float pBy0 = 0.f, pBw0 = 0.f, pBy1 = 0.f, pBw1 = 0.f;
    #pragma unroll
    for (int k = 0; k < NHM; ++k) {
      float4 a0 = {0, 0, 0, 0}, b0 = {0, 0, 0, 0};
      float4 a1 = {0, 0, 0, 0}, b1 = {0, 0, 0, 0};
      if (2 * k < J) {
        a0 = *reinterpret_cast<const float4*>(h3 + ((size_t)(JC + 2 * k) * HH + y0) * WW + x0);
        a1 = *reinterpret_cast<const float4*>(h3 + ((size_t)(JC + 2 * k) * HH + y0 + 1) * WW + x0);
      }
      if (2 * k + 1 < J) {
        b0 = *reinterpret_cast<const float4*>(h3 + ((size_t)(JC + 2 * k + 1) * HH + y0) * WW + x0);
        b1 = *reinterpret_cast<const float4*>(h3 + ((size_t)(JC + 2 * k + 1) * HH + y0 + 1) * WW + x0);
      }
      if (k < NHE) {
        heX0[k] = pack2(a0.x, b0.x); heZ0[k] = pack2(a0.z, b0.z);
        heX1[k] = pack2(a1.x, b1.x); heZ1[k] = pack2(a1.z, b1.z);
      }
      hmY0[k] = pack2(pBy0, a0.y); hmW0[k] = pack2(pBw0, a0.w);
      hmY1[k] = pack2(pBy1, a1.y); hmW1[k] = pack2(pBw1, a1.w);
      pBy0 = b0.y; pBw0 = b0.w; pBy1 = b1.y; pBw1 = b1.w;
    }
  }

  const float* vpa = v2 + (size_t)y0 * WW + x0;        // row y0, tap k
  const float* vpb = v2 + (size_t)(y0 + 1) * WW + x0;  // row y0+1, tap k-1
  int tb = (2 * tyq) * PAIRS + 2 * tx + QC;

  auto vla = [&](int k) -> float4 {
    if ((unsigned)k >= (unsigned)KFS) return float4{0, 0, 0, 0};
    return *reinterpret_cast<const float4*>(vpa + (size_t)k * VSTR);
  };
  auto vlb = [&](int k) -> float4 {
    if ((unsigned)(k - 1) >= (unsigned)KFS) return float4{0, 0, 0, 0};
    return *reinterpret_cast<const float4*>(vpb + (size_t)(k - 1) * VSTR);
  };

  float4 va0 = vla(0), vb0 = vlb(0);
  float4 va1 = vla(1), vb1 = vlb(1);

  auto step = [&](const float4& va, const float4& vb) {
    uint32_t ev[2 * NEV2];
    const uint2v* wp2 = reinterpret_cast<const uint2v*>(tile + tb);
    #pragma unroll
    for (int q = 0; q < NEV2; ++q) {
      const uint2v u = wp2[q];  // ds_read_b64, stride-2 lanes (2-way, free)
      ev[2 * q] = u.x;
      ev[2 * q + 1] = u.y;
    }

    float z00 = 0, z01 = 0, z02 = 0, z03 = 0;
    float z10 = 0, z11 = 0, z12 = 0, z13 = 0;
    #pragma unroll
    for (int q = 0; q < NHE; ++q) { z00 = fdot2(ev[q], heX0[q], z00); z10 = fdot2(ev[q], heX1[q], z10); }
    #pragma unroll
    for (int q = 0; q < NHM; ++q) { z01 = fdot2(ev[q], hmY0[q], z01); z11 = fdot2(ev[q], hmY1[q], z11); }
    #pragma unroll
    for (int q = 1; q <= NHE; ++q) { z02 = fdot2(ev[q], heZ0[q - 1], z02); z12 = fdot2(ev[q], heZ1[q - 1], z12); }
    #pragma unroll
    for (int q = 1; q <= NHM; ++q) { z03 = fdot2(ev[q], hmW0[q - 1], z03); z13 = fdot2(ev[q], hmW1[q - 1], z13); }

    acc0[0] = fmaf(va.x, z00, acc0[0]); acc0[1] = fmaf(va.y, z01, acc0[1]);
    acc0[2] = fmaf(va.z, z02, acc0[2]); acc0[3] = fmaf(va.w, z03, acc0[3]);
    acc1[0] = fmaf(vb.x, z10, acc1[0]); acc1[1] = fmaf(vb.y, z11, acc1[1]);
    acc1[2] = fmaf(vb.z, z12, acc1[2]); acc1[3] = fmaf(vb.w, z13, acc1[3]);
    tb += PAIRS;
  };

  // Rows k=0..KFS (52 steps): row k serves out0 tap k (k<51) and out1 tap k-1 (k>=1).
  #pragma unroll 1
  for (int ii = 0; ii < (KFS + 1) / 2; ++ii) {
    step(va0, vb0);
    va0 = vla(2 * ii + 2); vb0 = vlb(2 * ii + 2);
    step(va1, vb1);
    va1 = vla(2 * ii + 3); vb1 = vlb(2 * ii + 3);
  }
}

__global__ __launch_bounds__(NTHREADS, 3)
void sepconv_kernel(const float* __restrict__ in1, const float* __restrict__ in2,
                    const float* __restrict__ in3, float* __restrict__ out) {
  __shared__ uint32_t tile[CTILE + 12];  // +12: harmless b64 over-read pad

  const int t = threadIdx.x;
  const int tx = t & (NTX - 1);
  const int tyq = t >> 5;

  // XCD-grouping decode: consecutive dispatch slots on one XCD (lid%8 model)
  // become the 3 c-sibling blocks of one (x,y,b) group -> shared v/h in L2.
  const int lid = blockIdx.x;
  const int xcd = lid & 7;
  const int slot = lid >> 3;            // 0..95
  const int g = xcd * (NGRP / 8) + slot / NC;  // 0..255
  const int c = slot - NC * (slot / NC);
  const int xt = g & (XT - 1);
  const int yt = (g >> 2) & (YT - 1);
  const int b = g >> 7;

  const int x0t = xt * TW, y0t = yt * TH;
  const int x0 = x0t + tx * PX;
  const int y0 = y0t + 2 * tyq;

  const float* in1c = in1 + (size_t)(b * NC + c) * HP * WP;
  const float* v2 = in2 + (size_t)b * KFS * VSTR;
  const float* h3 = in3 + (size_t)b * KFS * VSTR;

  // Stage this block's channel tile: f32 global -> f16 pairs in LDS (linear).
  for (int e = t; e < NROWS * QPR; e += NTHREADS) {
    const int r = e / QPR;
    const int q = e - r * QPR;
    const float2 g2 = *reinterpret_cast<const float2*>(
        in1c + (size_t)(y0t + r) * WP + x0t + 2 * q);
    tile[r * PAIRS + q] = pack2(g2.x, g2.y);
  }
  __syncthreads();

  float acc0[PX] = {0, 0, 0, 0};
  float acc1[PX] = {0, 0, 0, 0};

  run_pass<0, 16>(tile, v2, h3, acc0, acc1, y0, x0, tx, tyq);
  run_pass<16, 16>(tile, v2, h3, acc0, acc1, y0, x0, tx, tyq);
  run_pass<32, 19>(tile, v2, h3, acc0, acc1, y0, x0, tx, tyq);

  float* op = out + ((size_t)(b * NC + c) * HH + y0) * WW + x0;
  float4 o0; o0.x = acc0[0]; o0.y = acc0[1]; o0.z = acc0[2]; o0.w = acc0[3];
  float4 o1; o1.x = acc1[0]; o1.y = acc1[1]; o1.z = acc1[2]; o1.w = acc1[3];
  *reinterpret_cast<float4*>(op) = o0;
  *reinterpret_cast<float4*>(op + WW) = o1;
}

}  // namespace

extern "C" void kernel_launch(void* const* d_in, const int* in_sizes, int n_in,
                              void* d_out, int out_size, void* d_ws, size_t ws_size,
                              hipStream_t stream) {
  const float* in1 = (const float*)d_in[0];
  const float* in2 = (const float*)d_in[1];
  const float* in3 = (const float*)d_in[2];
  float* out = (float*)d_out;

  sepconv_kernel<<<dim3(NWG), NTHREADS, 0, stream>>>(in1, in2, in3, out);
}